// Round 18
// baseline (124.712 us; speedup 1.0000x reference)
//
#include <hip/hip_runtime.h>
#include <hip/hip_bf16.h>
#include <stdint.h>

#define L_ 128
#define B_ 4
#define H_ 768
#define R_ 97
#define LN_EPS 1e-5f

typedef _Float16 f16x8 __attribute__((ext_vector_type(8)));
typedef _Float16 f16x4 __attribute__((ext_vector_type(4)));
typedef _Float16 f16x2 __attribute__((ext_vector_type(2)));
typedef float f32x4 __attribute__((ext_vector_type(4)));

extern "C" __device__ _Float16 __ocml_exp2_f16(_Float16);

__device__ inline f16x8 cvt8(float4 v0, float4 v1) {
  f16x8 o;
  o[0] = (_Float16)v0.x; o[1] = (_Float16)v0.y; o[2] = (_Float16)v0.z; o[3] = (_Float16)v0.w;
  o[4] = (_Float16)v1.x; o[5] = (_Float16)v1.y; o[6] = (_Float16)v1.z; o[7] = (_Float16)v1.w;
  return o;
}

// ================= prep (r16 verbatim): concat, packs, gamma/beta, gmax zero ============
__global__ __launch_bounds__(256) void prep_all(const float* __restrict__ h1,
                                                const float* __restrict__ h2,
                                                const float* __restrict__ Wr,
                                                const float* __restrict__ Wh,
                                                const float* __restrict__ Wo,
                                                const float* __restrict__ gamma,
                                                const float* __restrict__ beta,
                                                _Float16* __restrict__ ccH,
                                                _Float16* __restrict__ BpR,
                                                _Float16* __restrict__ BpW,
                                                _Float16* __restrict__ WoP,
                                                _Float16* __restrict__ gbH,
                                                unsigned int* __restrict__ gmaxU) {
  int blk = blockIdx.x;
  if (blk < 512) {                          // ---- concat h1|h2 -> f16 [512][1536]
    const float2* s1 = (const float2*)(h1 + (size_t)blk * H_);
    const float2* s2 = (const float2*)(h2 + (size_t)blk * H_);
    f16x2* d = (f16x2*)(ccH + (size_t)blk * (2 * H_));
    for (int i = threadIdx.x; i < H_ / 2; i += 256) {
      float2 v = s1[i]; f16x2 o; o[0] = (_Float16)v.x; o[1] = (_Float16)v.y; d[i] = o;
    }
    for (int i = threadIdx.x; i < H_ / 2; i += 256) {
      float2 v = s2[i]; f16x2 o; o[0] = (_Float16)v.x; o[1] = (_Float16)v.y; d[H_ / 2 + i] = o;
    }
    return;
  }
  blk -= 512;
  if (blk < 576) {                          // ---- pack Wr^T -> BpR: K=1536 (48 ks), NT=48
    int c = blk * 256 + threadIdx.x;
    int l = c & 63, u = c >> 6;
    int nt = u % 48, ks = u / 48;
    int n = nt * 16 + (l & 15);
    int k = ks * 32 + ((l >> 4) << 3);
    const float4* s = (const float4*)(Wr + (size_t)n * 1536 + k);
    *(f16x8*)(BpR + (size_t)c * 8) = cvt8(s[0], s[1]);
    return;
  }
  blk -= 576;
  if (blk < 576) {                          // ---- pack [W1^T|W2^T] -> BpW: K=768 (24 ks), NT=96
    int c = blk * 256 + threadIdx.x;
    int l = c & 63, u = c >> 6;
    int nt = u % 96, ks = u / 96;
    int n = nt * 16 + (l & 15);
    int k = ks * 32 + ((l >> 4) << 3);
    const float* src = (n < 768) ? (Wh + (size_t)n * 2304 + k)
                                 : (Wh + (size_t)(n - 768) * 2304 + 768 + k);
    const float4* s = (const float4*)src;
    *(f16x8*)(BpW + (size_t)c * 8) = cvt8(s[0], s[1]);
    return;
  }
  blk -= 576;
  if (blk < 48) {                           // ---- pack Wo -> WoP: K=768 (24 ks), NT=8 (pad 128)
    int c = blk * 256 + threadIdx.x;
    int l = c & 63, u = c >> 6;
    int nt = u & 7, ks = u >> 3;
    int n = nt * 16 + (l & 15);
    int k = ks * 32 + ((l >> 4) << 3);
    f16x8 o = {};
    if (n < R_) {
      const float4* s = (const float4*)(Wo + (size_t)n * 768 + k);
      o = cvt8(s[0], s[1]);
    }
    *(f16x8*)(WoP + (size_t)c * 8) = o;
    return;
  }
  blk -= 48;
  if (blk < 3) {                            // ---- gamma/beta -> f16
    int i = blk * 256 + threadIdx.x;
    if (i < H_) {
      gbH[i] = (_Float16)gamma[i];
      gbH[H_ + i] = (_Float16)beta[i];
    }
    return;
  }
  blk -= 3;                                 // ---- zero gmaxU (12 blocks)
  int i = blk * 256 + threadIdx.x;
  if (i < B_ * H_) gmaxU[i] = 0u;
}

// ================= gemm tile bodies (r14/r16 verified, packed B) ========================
__device__ __forceinline__ void gemm_g_tile(int nb, int mb,
                                            const _Float16* __restrict__ A,
                                            const _Float16* __restrict__ BpR,
                                            const float* __restrict__ br,
                                            unsigned int* __restrict__ gmaxU) {
  int w = threadIdx.x >> 6, l = threadIdx.x & 63;
  int row0 = mb * 32 + (w & 1) * 16;
  int nt0 = nb * 4 + (w >> 1) * 2;
  const f16x8* ap = (const f16x8*)(A + (size_t)(row0 + (l & 15)) * 1536 + (l >> 4) * 8);
  const f16x8* bp = (const f16x8*)(BpR + ((size_t)nt0 * 64 + l) * 8);
  f32x4 acc0 = {}, acc1 = {};
  f16x8 ac = ap[0], b0c = bp[0], b1c = bp[64];
  for (int ks = 0; ks < 48; ++ks) {
    f16x8 an = {}, b0n = {}, b1n = {};
    if (ks < 47) {
      an = ap[(ks + 1) * 4];
      b0n = bp[(size_t)(ks + 1) * 3072];
      b1n = bp[(size_t)(ks + 1) * 3072 + 64];
    }
    acc0 = __builtin_amdgcn_mfma_f32_16x16x32_f16(ac, b0c, acc0, 0, 0, 0);
    acc1 = __builtin_amdgcn_mfma_f32_16x16x32_f16(ac, b1c, acc1, 0, 0, 0);
    ac = an; b0c = b0n; b1c = b1n;
  }
#pragma unroll
  for (int q = 0; q < 2; ++q) {
    f32x4 acc = q ? acc1 : acc0;
    int col = nb * 64 + (w >> 1) * 32 + q * 16 + (l & 15);
#pragma unroll
    for (int r = 0; r < 4; ++r) {
      int row = row0 + (l >> 4) * 4 + r;
      float t = tanhf(acc[r] + br[col]) + 1.0f;   // >0 => uint-monotone
      atomicMax(&gmaxU[(row & 3) * H_ + col], __float_as_uint(t));
    }
  }
}

__device__ __forceinline__ void gemm_ab_tile(int nb, int mb,
                                             const _Float16* __restrict__ ccH,
                                             const _Float16* __restrict__ BpW,
                                             _Float16* __restrict__ aH,
                                             _Float16* __restrict__ bH) {
  int w = threadIdx.x >> 6, l = threadIdx.x & 63;
  int row0 = mb * 32 + (w & 1) * 16;
  int nt0 = nb * 4 + (w >> 1) * 2;
  const f16x8* ap = (const f16x8*)(ccH + (size_t)(row0 + (l & 15)) * 1536 + 768 + (l >> 4) * 8);
  const f16x8* bp = (const f16x8*)(BpW + ((size_t)nt0 * 64 + l) * 8);
  f32x4 acc0 = {}, acc1 = {};
  f16x8 ac = ap[0], b0c = bp[0], b1c = bp[64];
  for (int ks = 0; ks < 24; ++ks) {
    f16x8 an = {}, b0n = {}, b1n = {};
    if (ks < 23) {
      an = ap[(ks + 1) * 4];
      b0n = bp[(size_t)(ks + 1) * 6144];
      b1n = bp[(size_t)(ks + 1) * 6144 + 64];
    }
    acc0 = __builtin_amdgcn_mfma_f32_16x16x32_f16(ac, b0c, acc0, 0, 0, 0);
    acc1 = __builtin_amdgcn_mfma_f32_16x16x32_f16(ac, b1c, acc1, 0, 0, 0);
    ac = an; b0c = b0n; b1c = b1n;
  }
#pragma unroll
  for (int q = 0; q < 2; ++q) {
    f32x4 acc = q ? acc1 : acc0;
    int col = nb * 64 + (w >> 1) * 32 + q * 16 + (l & 15);
#pragma unroll
    for (int r = 0; r < 4; ++r) {
      int row = row0 + (l >> 4) * 4 + r;
      float v = acc[r];
      if (col < 768) aH[(size_t)row * H_ + col] = (_Float16)v;
      else           bH[(size_t)row * H_ + (col - 768)] = (_Float16)v;
    }
  }
}

// ---- one dispatch for both GEMMs (576 blocks) ----
__global__ __launch_bounds__(256) void gemm_both(const _Float16* __restrict__ ccH,
                                                 const _Float16* __restrict__ BpR,
                                                 const _Float16* __restrict__ BpW,
                                                 const float* __restrict__ br,
                                                 unsigned int* __restrict__ gmaxU,
                                                 _Float16* __restrict__ aH,
                                                 _Float16* __restrict__ bH) {
  int bid = blockIdx.x;
  if (bid < 192) {
    gemm_g_tile(bid % 12, bid / 12, ccH, BpR, br, gmaxU);
  } else {
    int j2 = bid - 192;
    gemm_ab_tile(j2 % 24, j2 / 24, ccH, BpW, aH, bH);
  }
}

// ================= gp[b][n] = dot(gmax[b,:], Wh[n,1536:2304]) + bh[n]  -> f16 ==========
__global__ __launch_bounds__(256) void gp_kernel(const float* __restrict__ Wh,
                                                 const unsigned int* __restrict__ gmaxU,
                                                 const float* __restrict__ bh,
                                                 _Float16* __restrict__ gpH) {
  int n = blockIdx.x;
  int w = threadIdx.x >> 6, l = threadIdx.x & 63;
  const float* wr = Wh + (size_t)n * 2304 + 1536;
  const unsigned int* gm = gmaxU + (size_t)w * H_;
  float s = 0.f;
#pragma unroll
  for (int t = 0; t < 12; ++t) {
    int i = l + 64 * t;
    s += wr[i] * (__uint_as_float(gm[i]) - 1.0f);
  }
#pragma unroll
  for (int off = 32; off; off >>= 1) s += __shfl_xor(s, off);
  if (l == 0) gpH[(size_t)w * H_ + n] = (_Float16)(s + bh[n]);
}

// ================= fused3: in-block LN stats prologue + r16 k-loop ======================
// Per 64-row block: 4 a'-rows (kk,b) and 16 b-rows x 4 b. Prologue computes, in f32:
//   wave w: S/Q of a'(kk,w) = aH + gpH  (64-lane butterfly)
//   quad (p = tid>>2): S/Q of bH(li0+(p>>2), p&3) and dot(a'(kk,p&3), bH-row)
// Then mu/rs per thread row; replaces the stats+dotab dispatches and the mu/rs
// round-trip. k-loop = r16 verbatim (phase-staged 32KB LDS, barrier-free k-steps)
// with x = a8 + b8 + gp8 (gp folded in; gpH is 6KB, L1-resident).
__global__ __launch_bounds__(256) void fused3(const _Float16* __restrict__ aH,
                                              const _Float16* __restrict__ bH,
                                              const _Float16* __restrict__ gpH,
                                              const _Float16* __restrict__ gbH,
                                              const _Float16* __restrict__ WoP,
                                              const float* __restrict__ bo,
                                              const float* __restrict__ mask,
                                              float* __restrict__ out) {
  __shared__ __align__(16) uint4 WoLds[2048];          // 32KB = 4 ks-chunks x 8KB
  __shared__ float SA[4], QA[4], pS[64], pQ[64], pD[64];
  int tid = threadIdx.x, w = tid >> 6, l = tid & 63;
  int m0 = blockIdx.x * 64;
  int kk = m0 >> 9;
  int li0 = (m0 >> 2) & 127;

  // ---- prologue 1: wave w -> S/Q of a'(kk,w) ----
  {
    const f16x4* ar = (const f16x4*)(aH + ((size_t)(kk * 4 + w)) * H_);
    const f16x4* gr = (const f16x4*)(gpH + (size_t)w * H_);
    float s = 0.f, q = 0.f;
#pragma unroll
    for (int t = 0; t < 3; ++t) {
      int i = t * 64 + l;
      f16x4 a4 = ar[i], g4 = gr[i];
#pragma unroll
      for (int j = 0; j < 4; ++j) {
        float x = (float)a4[j] + (float)g4[j];
        s += x; q += x * x;
      }
    }
#pragma unroll
    for (int off = 32; off; off >>= 1) { s += __shfl_xor(s, off); q += __shfl_xor(q, off); }
    if (l == 0) { SA[w] = s; QA[w] = q; }
  }
  // ---- prologue 2: quad p -> S/Q of bH row + cross-dot with a' ----
  {
    int p = tid >> 2, sub = tid & 3;        // quad = 4 consecutive lanes of one wave
    int lig = p & 15;                        // p = w*16 + (l>>2); row pair within block
    int pb = (p >> 4);                       // CAREFUL: need (li,b) covering all 64 rows
    // map p (0..63) -> rr4 = p: rows rr = p correspond to (li = li0 + (p>>2), b = p&3)
    int li = li0 + (p >> 2);
    int b = p & 3;
    (void)lig; (void)pb;
    const f16x4* brp = (const f16x4*)(bH + ((size_t)li * 4 + b) * H_);
    const f16x4* arp = (const f16x4*)(aH + ((size_t)(kk * 4 + b)) * H_);
    const f16x4* grp = (const f16x4*)(gpH + (size_t)b * H_);
    float sb = 0.f, qb = 0.f, d = 0.f;
    for (int i = 0; i < 48; ++i) {
      int idx = sub + 4 * i;
      f16x4 b4 = brp[idx], a4 = arp[idx], g4 = grp[idx];
#pragma unroll
      for (int j = 0; j < 4; ++j) {
        float bv = (float)b4[j];
        float av = (float)a4[j] + (float)g4[j];
        sb += bv; qb += bv * bv; d += av * bv;
      }
    }
    sb += __shfl_xor(sb, 1); sb += __shfl_xor(sb, 2);
    qb += __shfl_xor(qb, 1); qb += __shfl_xor(qb, 2);
    d  += __shfl_xor(d, 1);  d  += __shfl_xor(d, 2);
    if (sub == 0) { pS[p] = sb; pQ[p] = qb; pD[p] = d; }
  }
  __syncthreads();
  // ---- per-thread mu/rs for its A-frag row (rr = w*16 + (l&15)) ----
  int rr = w * 16 + (l & 15);
  int b = rr & 3;
  int pair = rr;                            // pair index == rr: (li0+(rr>>2), rr&3)
  float mu = (SA[b] + pS[pair]) * (1.f / H_);
  float q2 = QA[b] + pQ[pair] + 2.f * pD[pair];
  float var = fmaxf(q2 * (1.f / H_) - mu * mu, 0.f);
  float rs = rsqrtf(var + LN_EPS);

  int li = li0 + (rr >> 2);
  const f16x8* ap = (const f16x8*)(aH + ((size_t)(kk * 4 + b)) * H_ + (l >> 4) * 8);
  const f16x8* bp = (const f16x8*)(bH + ((size_t)li * 4 + b) * H_ + (l >> 4) * 8);
  const f16x8* gpp = (const f16x8*)(gpH + (size_t)b * H_ + (l >> 4) * 8);
  const f16x8* gp8 = (const f16x8*)(gbH + (l >> 4) * 8);
  const f16x8* be8 = (const f16x8*)(gbH + H_ + (l >> 4) * 8);
  _Float16 muh = (_Float16)mu, rsh = (_Float16)rs;
  _Float16 l2e = (_Float16)1.44269504f;
  f16x8 mu8, rs8, zero8, one8, l2e8;
#pragma unroll
  for (int j = 0; j < 8; ++j) {
    mu8[j] = muh; rs8[j] = rsh;
    zero8[j] = (_Float16)0.f; one8[j] = (_Float16)1.f; l2e8[j] = l2e;
  }

  const uint4* wog = (const uint4*)WoP;                // 512 uint4 per ks-chunk
  f16x8 a8 = ap[0], b8 = bp[0], p8 = gpp[0], g8 = gp8[0], e8 = be8[0];

  f32x4 acc[7] = {};
  for (int ph = 0; ph < 6; ++ph) {
    __syncthreads();                                   // all waves done reading prev phase
    const uint4* gsrc = wog + (size_t)ph * 2048;
#pragma unroll
    for (int g = 0; g < 2; ++g) {
      uint4 v0 = gsrc[(g * 4 + 0) * 256 + tid];
      uint4 v1 = gsrc[(g * 4 + 1) * 256 + tid];
      uint4 v2 = gsrc[(g * 4 + 2) * 256 + tid];
      uint4 v3 = gsrc[(g * 4 + 3) * 256 + tid];
      WoLds[(g * 4 + 0) * 256 + tid] = v0;
      WoLds[(g * 4 + 1) * 256 + tid] = v1;
      WoLds[(g * 4 + 2) * 256 + tid] = v2;
      WoLds[(g * 4 + 3) * 256 + tid] = v3;
    }
    __syncthreads();                                   // staged data visible
#pragma unroll
    for (int s = 0; s < 4; ++s) {
      int ks = ph * 4 + s;
      f16x8 an = {}, bn = {}, pn = {}, gn = {}, en = {};
      if (ks < 23) {                                   // prefetch ks+1 operands
        an = ap[(ks + 1) * 4];
        bn = bp[(ks + 1) * 4];
        pn = gpp[(ks + 1) * 4];
        gn = gp8[(ks + 1) * 4];
        en = be8[(ks + 1) * 4];
      }
      // packed-f16 build: x = a+b+gp; y = (x-mu)*rs*gamma + beta; elu branchless
      f16x8 x = (a8 + b8) + p8;
      f16x8 c1 = rs8 * g8;
      f16x8 yv = (x - mu8) * c1 + e8;
      f16x8 y2 = yv * l2e8;
      f16x8 ex;
#pragma unroll
      for (int j = 0; j < 8; ++j) ex[j] = __ocml_exp2_f16(y2[j]);
      ex = ex - one8;
      f16x8 av = __builtin_elementwise_max(yv, zero8) + __builtin_elementwise_min(ex, zero8);
      const f16x8* bvp = (const f16x8*)&WoLds[s * 512];
#pragma unroll
      for (int q = 0; q < 7; ++q) {
        f16x8 bv = bvp[q * 64 + l];
        acc[q] = __builtin_amdgcn_mfma_f32_16x16x32_f16(av, bv, acc[q], 0, 0, 0);
      }
      a8 = an; b8 = bn; p8 = pn; g8 = gn; e8 = en;
    }
  }
  // ---- epilogue: bias, sigmoid, mask ----
  float mv[4];
#pragma unroll
  for (int r = 0; r < 4; ++r) {
    int row = m0 + w * 16 + (l >> 4) * 4 + r;
    int bb = row & 3, ll = (row >> 2) & 127, kx = row >> 9;
    mv[r] = mask[kx * 4 + bb] * mask[ll * 4 + bb];
  }
#pragma unroll
  for (int q = 0; q < 7; ++q) {
    int col = q * 16 + (l & 15);
    if (col < R_) {
      float bov = bo[col];
#pragma unroll
      for (int r = 0; r < 4; ++r) {
        int row = m0 + w * 16 + (l >> 4) * 4 + r;
        float z = acc[q][r] + bov;
        out[(size_t)row * R_ + col] = mv[r] / (1.f + __expf(-z));
      }
    }
  }
}

extern "C" void kernel_launch(void* const* d_in, const int* in_sizes, int n_in,
                              void* d_out, int out_size, void* d_ws, size_t ws_size,
                              hipStream_t stream) {
  const float* h1    = (const float*)d_in[0];
  const float* h2    = (const float*)d_in[1];
  const float* mask  = (const float*)d_in[2];
  const float* Wr    = (const float*)d_in[3];
  const float* br    = (const float*)d_in[4];
  const float* Wh    = (const float*)d_in[5];
  const float* bh    = (const float*)d_in[6];
  const float* gamma = (const float*)d_in[7];
  const float* beta  = (const float*)d_in[8];
  const float* Wo    = (const float*)d_in[9];
  const float* bo    = (const float*)d_in[10];
  float* out = (float*)d_out;
  char* ws = (char*)d_ws;

  // ws layout (bytes, 16B-aligned chunks)
  _Float16* ccH = (_Float16*)ws;                    size_t off = 512 * 1536 * 2;        // 1.5MB
  _Float16* BpR = (_Float16*)(ws + off);            off += (size_t)1536 * 768 * 2;      // 2.25MB
  _Float16* BpW = (_Float16*)(ws + off);            off += (size_t)768 * 1536 * 2;      // 2.25MB
  _Float16* WoP = (_Float16*)(ws + off);            off += 768 * 128 * 2;               // 192KB
  _Float16* gbH = (_Float16*)(ws + off);            off += 4096;
  _Float16* aH  = (_Float16*)(ws + off);            off += 512 * 768 * 2;
  _Float16* bH  = (_Float16*)(ws + off);            off += 512 * 768 * 2;
  unsigned int* gmaxU = (unsigned int*)(ws + off);  off += 3072 * 4;
  _Float16* gpH = (_Float16*)(ws + off);            off += 4 * 768 * 2;

  prep_all<<<512 + 576 + 576 + 48 + 3 + 12, 256, 0, stream>>>(h1, h2, Wr, Wh, Wo, gamma, beta,
                                                              ccH, BpR, BpW, WoP, gbH, gmaxU);

  gemm_both<<<576, 256, 0, stream>>>(ccH, BpR, BpW, br, gmaxU, aH, bH);
  gp_kernel<<<768, 256, 0, stream>>>(Wh, gmaxU, bh, gpH);

  fused3<<<1024, 256, 0, stream>>>(aH, bH, gpH, gbH, WoP, bo, mask, out);
}

// Round 19
// 87.116 us; speedup vs baseline: 1.4316x; 1.4316x over previous
//
#include <hip/hip_runtime.h>
#include <hip/hip_bf16.h>
#include <stdint.h>

#define L_ 128
#define B_ 4
#define H_ 768
#define R_ 97
#define LN_EPS 1e-5f

typedef _Float16 f16x8 __attribute__((ext_vector_type(8)));
typedef _Float16 f16x4 __attribute__((ext_vector_type(4)));
typedef _Float16 f16x2 __attribute__((ext_vector_type(2)));
typedef float f32x4 __attribute__((ext_vector_type(4)));

extern "C" __device__ _Float16 __ocml_exp2_f16(_Float16);

__device__ inline f16x8 cvt8(float4 v0, float4 v1) {
  f16x8 o;
  o[0] = (_Float16)v0.x; o[1] = (_Float16)v0.y; o[2] = (_Float16)v0.z; o[3] = (_Float16)v0.w;
  o[4] = (_Float16)v1.x; o[5] = (_Float16)v1.y; o[6] = (_Float16)v1.z; o[7] = (_Float16)v1.w;
  return o;
}

// ================= prep (r16 verbatim): concat, packs, gamma/beta, gmax zero ============
__global__ __launch_bounds__(256) void prep_all(const float* __restrict__ h1,
                                                const float* __restrict__ h2,
                                                const float* __restrict__ Wr,
                                                const float* __restrict__ Wh,
                                                const float* __restrict__ Wo,
                                                const float* __restrict__ gamma,
                                                const float* __restrict__ beta,
                                                _Float16* __restrict__ ccH,
                                                _Float16* __restrict__ BpR,
                                                _Float16* __restrict__ BpW,
                                                _Float16* __restrict__ WoP,
                                                _Float16* __restrict__ gbH,
                                                unsigned int* __restrict__ gmaxU) {
  int blk = blockIdx.x;
  if (blk < 512) {                          // ---- concat h1|h2 -> f16 [512][1536]
    const float2* s1 = (const float2*)(h1 + (size_t)blk * H_);
    const float2* s2 = (const float2*)(h2 + (size_t)blk * H_);
    f16x2* d = (f16x2*)(ccH + (size_t)blk * (2 * H_));
    for (int i = threadIdx.x; i < H_ / 2; i += 256) {
      float2 v = s1[i]; f16x2 o; o[0] = (_Float16)v.x; o[1] = (_Float16)v.y; d[i] = o;
    }
    for (int i = threadIdx.x; i < H_ / 2; i += 256) {
      float2 v = s2[i]; f16x2 o; o[0] = (_Float16)v.x; o[1] = (_Float16)v.y; d[H_ / 2 + i] = o;
    }
    return;
  }
  blk -= 512;
  if (blk < 576) {                          // ---- pack Wr^T -> BpR: K=1536 (48 ks), NT=48
    int c = blk * 256 + threadIdx.x;
    int l = c & 63, u = c >> 6;
    int nt = u % 48, ks = u / 48;
    int n = nt * 16 + (l & 15);
    int k = ks * 32 + ((l >> 4) << 3);
    const float4* s = (const float4*)(Wr + (size_t)n * 1536 + k);
    *(f16x8*)(BpR + (size_t)c * 8) = cvt8(s[0], s[1]);
    return;
  }
  blk -= 576;
  if (blk < 576) {                          // ---- pack [W1^T|W2^T] -> BpW: K=768 (24 ks), NT=96
    int c = blk * 256 + threadIdx.x;
    int l = c & 63, u = c >> 6;
    int nt = u % 96, ks = u / 96;
    int n = nt * 16 + (l & 15);
    int k = ks * 32 + ((l >> 4) << 3);
    const float* src = (n < 768) ? (Wh + (size_t)n * 2304 + k)
                                 : (Wh + (size_t)(n - 768) * 2304 + 768 + k);
    const float4* s = (const float4*)src;
    *(f16x8*)(BpW + (size_t)c * 8) = cvt8(s[0], s[1]);
    return;
  }
  blk -= 576;
  if (blk < 48) {                           // ---- pack Wo -> WoP: K=768 (24 ks), NT=8 (pad 128)
    int c = blk * 256 + threadIdx.x;
    int l = c & 63, u = c >> 6;
    int nt = u & 7, ks = u >> 3;
    int n = nt * 16 + (l & 15);
    int k = ks * 32 + ((l >> 4) << 3);
    f16x8 o = {};
    if (n < R_) {
      const float4* s = (const float4*)(Wo + (size_t)n * 768 + k);
      o = cvt8(s[0], s[1]);
    }
    *(f16x8*)(WoP + (size_t)c * 8) = o;
    return;
  }
  blk -= 48;
  if (blk < 3) {                            // ---- gamma/beta -> f16
    int i = blk * 256 + threadIdx.x;
    if (i < H_) {
      gbH[i] = (_Float16)gamma[i];
      gbH[H_ + i] = (_Float16)beta[i];
    }
    return;
  }
  blk -= 3;                                 // ---- zero gmaxU (12 blocks)
  int i = blk * 256 + threadIdx.x;
  if (i < B_ * H_) gmaxU[i] = 0u;
}

// ================= gemm tile bodies (r14/r16 verified, packed B) ========================
__device__ __forceinline__ void gemm_g_tile(int nb, int mb,
                                            const _Float16* __restrict__ A,
                                            const _Float16* __restrict__ BpR,
                                            const float* __restrict__ br,
                                            unsigned int* __restrict__ gmaxU) {
  int w = threadIdx.x >> 6, l = threadIdx.x & 63;
  int row0 = mb * 32 + (w & 1) * 16;
  int nt0 = nb * 4 + (w >> 1) * 2;
  const f16x8* ap = (const f16x8*)(A + (size_t)(row0 + (l & 15)) * 1536 + (l >> 4) * 8);
  const f16x8* bp = (const f16x8*)(BpR + ((size_t)nt0 * 64 + l) * 8);
  f32x4 acc0 = {}, acc1 = {};
  f16x8 ac = ap[0], b0c = bp[0], b1c = bp[64];
  for (int ks = 0; ks < 48; ++ks) {
    f16x8 an = {}, b0n = {}, b1n = {};
    if (ks < 47) {
      an = ap[(ks + 1) * 4];
      b0n = bp[(size_t)(ks + 1) * 3072];
      b1n = bp[(size_t)(ks + 1) * 3072 + 64];
    }
    acc0 = __builtin_amdgcn_mfma_f32_16x16x32_f16(ac, b0c, acc0, 0, 0, 0);
    acc1 = __builtin_amdgcn_mfma_f32_16x16x32_f16(ac, b1c, acc1, 0, 0, 0);
    ac = an; b0c = b0n; b1c = b1n;
  }
#pragma unroll
  for (int q = 0; q < 2; ++q) {
    f32x4 acc = q ? acc1 : acc0;
    int col = nb * 64 + (w >> 1) * 32 + q * 16 + (l & 15);
#pragma unroll
    for (int r = 0; r < 4; ++r) {
      int row = row0 + (l >> 4) * 4 + r;
      float t = tanhf(acc[r] + br[col]) + 1.0f;   // >0 => uint-monotone
      atomicMax(&gmaxU[(row & 3) * H_ + col], __float_as_uint(t));
    }
  }
}

__device__ __forceinline__ void gemm_ab_tile(int nb, int mb,
                                             const _Float16* __restrict__ ccH,
                                             const _Float16* __restrict__ BpW,
                                             _Float16* __restrict__ aH,
                                             _Float16* __restrict__ bH) {
  int w = threadIdx.x >> 6, l = threadIdx.x & 63;
  int row0 = mb * 32 + (w & 1) * 16;
  int nt0 = nb * 4 + (w >> 1) * 2;
  const f16x8* ap = (const f16x8*)(ccH + (size_t)(row0 + (l & 15)) * 1536 + 768 + (l >> 4) * 8);
  const f16x8* bp = (const f16x8*)(BpW + ((size_t)nt0 * 64 + l) * 8);
  f32x4 acc0 = {}, acc1 = {};
  f16x8 ac = ap[0], b0c = bp[0], b1c = bp[64];
  for (int ks = 0; ks < 24; ++ks) {
    f16x8 an = {}, b0n = {}, b1n = {};
    if (ks < 23) {
      an = ap[(ks + 1) * 4];
      b0n = bp[(size_t)(ks + 1) * 6144];
      b1n = bp[(size_t)(ks + 1) * 6144 + 64];
    }
    acc0 = __builtin_amdgcn_mfma_f32_16x16x32_f16(ac, b0c, acc0, 0, 0, 0);
    acc1 = __builtin_amdgcn_mfma_f32_16x16x32_f16(ac, b1c, acc1, 0, 0, 0);
    ac = an; b0c = b0n; b1c = b1n;
  }
#pragma unroll
  for (int q = 0; q < 2; ++q) {
    f32x4 acc = q ? acc1 : acc0;
    int col = nb * 64 + (w >> 1) * 32 + q * 16 + (l & 15);
#pragma unroll
    for (int r = 0; r < 4; ++r) {
      int row = row0 + (l >> 4) * 4 + r;
      float v = acc[r];
      if (col < 768) aH[(size_t)row * H_ + col] = (_Float16)v;
      else           bH[(size_t)row * H_ + (col - 768)] = (_Float16)v;
    }
  }
}

// ---- one dispatch for both GEMMs (576 blocks) ----
__global__ __launch_bounds__(256) void gemm_both(const _Float16* __restrict__ ccH,
                                                 const _Float16* __restrict__ BpR,
                                                 const _Float16* __restrict__ BpW,
                                                 const float* __restrict__ br,
                                                 unsigned int* __restrict__ gmaxU,
                                                 _Float16* __restrict__ aH,
                                                 _Float16* __restrict__ bH) {
  int bid = blockIdx.x;
  if (bid < 192) {
    gemm_g_tile(bid % 12, bid / 12, ccH, BpR, br, gmaxU);
  } else {
    int j2 = bid - 192;
    gemm_ab_tile(j2 % 24, j2 / 24, ccH, BpW, aH, bH);
  }
}

// ================= gp[b][n] = dot(gmax[b,:], Wh[n,1536:2304]) + bh[n] =================
__global__ __launch_bounds__(256) void gp_kernel(const float* __restrict__ Wh,
                                                 const unsigned int* __restrict__ gmaxU,
                                                 const float* __restrict__ bh,
                                                 float* __restrict__ gpv) {
  int n = blockIdx.x;
  int w = threadIdx.x >> 6, l = threadIdx.x & 63;
  const float* wr = Wh + (size_t)n * 2304 + 1536;
  const unsigned int* gm = gmaxU + (size_t)w * H_;
  float s = 0.f;
#pragma unroll
  for (int t = 0; t < 12; ++t) {
    int i = l + 64 * t;
    s += wr[i] * (__uint_as_float(gm[i]) - 1.0f);
  }
#pragma unroll
  for (int off = 32; off; off >>= 1) s += __shfl_xor(s, off);
  if (l == 0) gpv[(size_t)w * H_ + n] = s + bh[n];
}

// ================= stats: aH2 = f16(aH + gp); S,Q per row for aH2 (0..511), bH (512..1023)
__global__ __launch_bounds__(256) void stats(const _Float16* __restrict__ aH,
                                             const _Float16* __restrict__ bH,
                                             const float* __restrict__ gpv,
                                             _Float16* __restrict__ aH2,
                                             float* __restrict__ S,
                                             float* __restrict__ Q) {
  int r = blockIdx.x * 4 + (threadIdx.x >> 6);
  int l = threadIdx.x & 63;
  float s = 0.f, q = 0.f;
  if (r < 512) {
    int b = r & 3;
    const f16x4* ap = (const f16x4*)(aH + (size_t)r * H_);
    const float4* gp4 = (const float4*)(gpv + (size_t)b * H_);
    f16x4* op = (f16x4*)(aH2 + (size_t)r * H_);
#pragma unroll
    for (int t = 0; t < 3; ++t) {
      int i = t * 64 + l;
      f16x4 av = ap[i];
      float4 g4 = gp4[i];
      f16x4 o;
      o[0] = (_Float16)((float)av[0] + g4.x);
      o[1] = (_Float16)((float)av[1] + g4.y);
      o[2] = (_Float16)((float)av[2] + g4.z);
      o[3] = (_Float16)((float)av[3] + g4.w);
      op[i] = o;
#pragma unroll
      for (int j = 0; j < 4; ++j) { float y = (float)o[j]; s += y; q += y * y; }
    }
  } else {
    const f16x4* bp = (const f16x4*)(bH + (size_t)(r - 512) * H_);
#pragma unroll
    for (int t = 0; t < 3; ++t) {
      f16x4 bv = bp[t * 64 + l];
#pragma unroll
      for (int j = 0; j < 4; ++j) { float y = (float)bv[j]; s += y; q += y * y; }
    }
  }
#pragma unroll
  for (int off = 32; off; off >>= 1) {
    s += __shfl_xor(s, off);
    q += __shfl_xor(q, off);
  }
  if (l == 0) { S[r] = s; Q[r] = q; }
}

// ================= dotab: cross dot -> mu/rs per (k,l,b) row via MFMA ===================
__global__ __launch_bounds__(256) void dotab(const _Float16* __restrict__ aH2,
                                             const _Float16* __restrict__ bH,
                                             const float* __restrict__ S,
                                             const float* __restrict__ Q,
                                             float* __restrict__ mu_arr,
                                             float* __restrict__ rs_arr) {
  int w = threadIdx.x >> 6, l = threadIdx.x & 63;
  int ltq = blockIdx.x, kt = blockIdx.y, b = blockIdx.z;
  int lt = ltq * 4 + w;
  const f16x8* ap = (const f16x8*)(aH2 + ((size_t)(kt * 16 + (l & 15)) * 4 + b) * H_ + (l >> 4) * 8);
  const f16x8* bp = (const f16x8*)(bH + ((size_t)(lt * 16 + (l & 15)) * 4 + b) * H_ + (l >> 4) * 8);
  f32x4 acc = {};
  f16x8 a0 = ap[0], b0 = bp[0], a1 = ap[4], b1 = bp[4];
  for (int ks = 0; ks < 24; ++ks) {
    f16x8 a2 = {}, b2 = {};
    if (ks < 22) { a2 = ap[(ks + 2) * 4]; b2 = bp[(ks + 2) * 4]; }
    acc = __builtin_amdgcn_mfma_f32_16x16x32_f16(a0, b0, acc, 0, 0, 0);
    a0 = a1; b0 = b1; a1 = a2; b1 = b2;
  }
#pragma unroll
  for (int r = 0; r < 4; ++r) {
    int k = kt * 16 + (l >> 4) * 4 + r;
    int lg = lt * 16 + (l & 15);
    int arow = k * 4 + b, brow = lg * 4 + b;
    float mu = (S[arow] + S[512 + brow]) * (1.f / H_);
    float q2 = Q[arow] + Q[512 + brow] + 2.f * acc[r];
    float var = fmaxf(q2 * (1.f / H_) - mu * mu, 0.f);   // guard: true var >= 0
    float rs = rsqrtf(var + LN_EPS);
    size_t idx = (size_t)k * 512 + (size_t)lg * 4 + b;
    mu_arr[idx] = mu;
    rs_arr[idx] = rs;
  }
}

// ================= fused2: M=32 rows per WAVE (2 A-frags), each bv feeds 2 MFMAs ========
// r16 phase-staged structure (32KB LDS, 6 phases x 4 barrier-free k-steps), but wave w
// owns rows [m0+32w, m0+32w+32): halves the dominant ds_read pipe per output and gives
// each wave 2 independent MFMA chains (ILP). A-operand prefetch dropped (r11: null) to
// keep VGPR ~110-130 (r6 spill lesson). Block 256 thr / 128 rows, grid 512.
__global__ __launch_bounds__(256) void fused2(const _Float16* __restrict__ aH2,
                                              const _Float16* __restrict__ bH,
                                              const _Float16* __restrict__ gbH,
                                              const _Float16* __restrict__ WoP,
                                              const float* __restrict__ bo,
                                              const float* __restrict__ mask,
                                              const float* __restrict__ mu_arr,
                                              const float* __restrict__ rs_arr,
                                              float* __restrict__ out) {
  __shared__ __align__(16) uint4 WoLds[2048];          // 32KB = 4 ks-chunks x 8KB
  int tid = threadIdx.x, w = tid >> 6, l = tid & 63;
  int m0 = blockIdx.x * 128;
  int kk = m0 >> 9;                                    // constant within block
  int row0 = m0 + w * 32 + (l & 15);
  int row1 = row0 + 16;
  int b0 = row0 & 3, li0 = (row0 >> 2) & 127;
  int b1 = row1 & 3, li1 = (row1 >> 2) & 127;
  const f16x8* ap0 = (const f16x8*)(aH2 + ((size_t)kk * 4 + b0) * H_ + (l >> 4) * 8);
  const f16x8* bp0 = (const f16x8*)(bH + ((size_t)li0 * 4 + b0) * H_ + (l >> 4) * 8);
  const f16x8* ap1 = (const f16x8*)(aH2 + ((size_t)kk * 4 + b1) * H_ + (l >> 4) * 8);
  const f16x8* bp1 = (const f16x8*)(bH + ((size_t)li1 * 4 + b1) * H_ + (l >> 4) * 8);
  const f16x8* gp8 = (const f16x8*)(gbH + (l >> 4) * 8);
  const f16x8* be8 = (const f16x8*)(gbH + H_ + (l >> 4) * 8);
  float mu0f = mu_arr[row0], rs0f = rs_arr[row0];
  float mu1f = mu_arr[row1], rs1f = rs_arr[row1];
  _Float16 l2e = (_Float16)1.44269504f;
  f16x8 mu80, rs80, mu81, rs81, zero8, one8, l2e8;
#pragma unroll
  for (int j = 0; j < 8; ++j) {
    mu80[j] = (_Float16)mu0f; rs80[j] = (_Float16)rs0f;
    mu81[j] = (_Float16)mu1f; rs81[j] = (_Float16)rs1f;
    zero8[j] = (_Float16)0.f; one8[j] = (_Float16)1.f; l2e8[j] = l2e;
  }

  const uint4* wog = (const uint4*)WoP;                // 512 uint4 per ks-chunk

  f32x4 acc0[7] = {};
  f32x4 acc1[7] = {};
  for (int ph = 0; ph < 6; ++ph) {
    // ---- stage this phase's 4 chunks (2048 uint4; 8/thread) ----
    __syncthreads();                                   // all waves done reading prev phase
    const uint4* gsrc = wog + (size_t)ph * 2048;
#pragma unroll
    for (int g = 0; g < 2; ++g) {
      uint4 v0 = gsrc[(g * 4 + 0) * 256 + tid];
      uint4 v1 = gsrc[(g * 4 + 1) * 256 + tid];
      uint4 v2 = gsrc[(g * 4 + 2) * 256 + tid];
      uint4 v3 = gsrc[(g * 4 + 3) * 256 + tid];
      WoLds[(g * 4 + 0) * 256 + tid] = v0;
      WoLds[(g * 4 + 1) * 256 + tid] = v1;
      WoLds[(g * 4 + 2) * 256 + tid] = v2;
      WoLds[(g * 4 + 3) * 256 + tid] = v3;
    }
    __syncthreads();                                   // staged data visible
    // ---- 4 straight-line k-steps, NO barriers ----
#pragma unroll
    for (int s = 0; s < 4; ++s) {
      int ks = ph * 4 + s;
      // inline A-operand loads (prefetch was null per r11)
      f16x8 a80 = ap0[ks * 4];
      f16x8 b80 = bp0[ks * 4];
      f16x8 a81 = ap1[ks * 4];
      f16x8 b81 = bp1[ks * 4];
      f16x8 g8 = gp8[ks * 4];
      f16x8 e8 = be8[ks * 4];
      // packed-f16 builds (two rows)
      f16x8 x0 = a80 + b80;
      f16x8 x1 = a81 + b81;
      f16x8 c10 = rs80 * g8;
      f16x8 c11 = rs81 * g8;
      f16x8 yv0 = (x0 - mu80) * c10 + e8;
      f16x8 yv1 = (x1 - mu81) * c11 + e8;
      f16x8 y20 = yv0 * l2e8;
      f16x8 y21 = yv1 * l2e8;
      f16x8 ex0, ex1;
#pragma unroll
      for (int j = 0; j < 8; ++j) {
        ex0[j] = __ocml_exp2_f16(y20[j]);
        ex1[j] = __ocml_exp2_f16(y21[j]);
      }
      ex0 = ex0 - one8;
      ex1 = ex1 - one8;
      f16x8 av0 = __builtin_elementwise_max(yv0, zero8) + __builtin_elementwise_min(ex0, zero8);
      f16x8 av1 = __builtin_elementwise_max(yv1, zero8) + __builtin_elementwise_min(ex1, zero8);
      const f16x8* bvp = (const f16x8*)&WoLds[s * 512];
#pragma unroll
      for (int q = 0; q < 7; ++q) {
        f16x8 bv = bvp[q * 64 + l];                    // one LDS read -> 2 MFMAs
        acc0[q] = __builtin_amdgcn_mfma_f32_16x16x32_f16(av0, bv, acc0[q], 0, 0, 0);
        acc1[q] = __builtin_amdgcn_mfma_f32_16x16x32_f16(av1, bv, acc1[q], 0, 0, 0);
      }
    }
  }
  // ---- epilogue: bias, sigmoid, mask (two row sets) ----
#pragma unroll
  for (int set = 0; set < 2; ++set) {
    int rbase = m0 + w * 32 + set * 16;
    float mv[4];
#pragma unroll
    for (int r = 0; r < 4; ++r) {
      int row = rbase + (l >> 4) * 4 + r;
      int bb = row & 3, ll = (row >> 2) & 127, kx = row >> 9;
      mv[r] = mask[kx * 4 + bb] * mask[ll * 4 + bb];
    }
#pragma unroll
    for (int q = 0; q < 7; ++q) {
      int col = q * 16 + (l & 15);
      if (col < R_) {
        float bov = bo[col];
#pragma unroll
        for (int r = 0; r < 4; ++r) {
          int row = rbase + (l >> 4) * 4 + r;
          float z = (set ? acc1[q][r] : acc0[q][r]) + bov;
          out[(size_t)row * R_ + col] = mv[r] / (1.f + __expf(-z));
        }
      }
    }
  }
}

extern "C" void kernel_launch(void* const* d_in, const int* in_sizes, int n_in,
                              void* d_out, int out_size, void* d_ws, size_t ws_size,
                              hipStream_t stream) {
  const float* h1    = (const float*)d_in[0];
  const float* h2    = (const float*)d_in[1];
  const float* mask  = (const float*)d_in[2];
  const float* Wr    = (const float*)d_in[3];
  const float* br    = (const float*)d_in[4];
  const float* Wh    = (const float*)d_in[5];
  const float* bh    = (const float*)d_in[6];
  const float* gamma = (const float*)d_in[7];
  const float* beta  = (const float*)d_in[8];
  const float* Wo    = (const float*)d_in[9];
  const float* bo    = (const float*)d_in[10];
  float* out = (float*)d_out;
  char* ws = (char*)d_ws;

  // ws layout (bytes, 16B-aligned chunks)
  _Float16* ccH = (_Float16*)ws;                    size_t off = 512 * 1536 * 2;        // 1.5MB
  _Float16* BpR = (_Float16*)(ws + off);            off += (size_t)1536 * 768 * 2;      // 2.25MB
  _Float16* BpW = (_Float16*)(ws + off);            off += (size_t)768 * 1536 * 2;      // 2.25MB
  _Float16* WoP = (_Float16*)(ws + off);            off += 768 * 128 * 2;               // 192KB
  _Float16* gbH = (_Float16*)(ws + off);            off += 4096;
  _Float16* aH  = (_Float16*)(ws + off);            off += 512 * 768 * 2;
  _Float16* bH  = (_Float16*)(ws + off);            off += 512 * 768 * 2;
  _Float16* aH2 = (_Float16*)(ws + off);            off += 512 * 768 * 2;
  unsigned int* gmaxU = (unsigned int*)(ws + off);  off += 3072 * 4;
  float* gpv = (float*)(ws + off);                  off += 3072 * 4;
  float* S   = (float*)(ws + off);                  off += 1024 * 4;
  float* Q   = (float*)(ws + off);                  off += 1024 * 4;
  float* mu_arr = (float*)(ws + off);               off += 65536 * 4;
  float* rs_arr = (float*)(ws + off);               off += 65536 * 4;

  prep_all<<<512 + 576 + 576 + 48 + 3 + 12, 256, 0, stream>>>(h1, h2, Wr, Wh, Wo, gamma, beta,
                                                              ccH, BpR, BpW, WoP, gbH, gmaxU);

  gemm_both<<<576, 256, 0, stream>>>(ccH, BpR, BpW, br, gmaxU, aH, bH);
  gp_kernel<<<768, 256, 0, stream>>>(Wh, gmaxU, bh, gpv);
  stats<<<256, 256, 0, stream>>>(aH, bH, gpv, aH2, S, Q);
  dotab<<<dim3(2, 8, 4), 256, 0, stream>>>(aH2, bH, S, Q, mu_arr, rs_arr);

  fused2<<<512, 256, 0, stream>>>(aH2, bH, gbH, WoP, bo, mask, mu_arr, rs_arr, out);
}